// Round 5
// baseline (179.821 us; speedup 1.0000x reference)
//
#include <hip/hip_runtime.h>
#include <float.h>

// VectorQuantizer: x [64,64,32,32] f32, weight [1024,64] f32
// out[n] = weight[argmin_k ||x_n - w_k||^2]
// score = 0.5||w||^2 + (-x).w via split-bf16 MFMA, K=192 (hi.hi + lo_x.hi_w +
// hi_x.lo_w; lo.lo dropped ~1e-5 << EPS). wn folded into MFMA C-init.
// B-fragments load straight from global (L2-resident 256KB) -> NO barriers,
// NO LDS in the K-loop (the R4 dbuf stalled on vmcnt(0)-before-s_barrier).
// Latents with top-2 margin < EPS get exact fp32 rescore (rescue kernel).
#define NLAT   65536
#define KCODES 1024
#define DIM    64
#define HW     1024
#define LPB    128
#define XROW   136          // XE padded row (shorts): 272 B
#define EPS    2.0e-3f
#define RESCUE_CAP 4096

typedef float f32x4 __attribute__((ext_vector_type(4)));
typedef short short8 __attribute__((ext_vector_type(8)));

static __device__ __forceinline__ unsigned short f2bf(float f) {
    unsigned int u = __float_as_uint(f);
    return (unsigned short)((u + 0x7fffu + ((u >> 16) & 1u)) >> 16);   // RNE
}
static __device__ __forceinline__ float bf2f(unsigned short h) {
    return __uint_as_float(((unsigned int)h) << 16);
}

// ---------------------------------------------------------------------------
// Prep: WEg[k] = 128 shorts: [0..63]=hi(w[k][d]), [64..127]=lo. wn=0.5||w||^2.
__global__ void vq_prep(const float* __restrict__ w, unsigned short* __restrict__ WEg,
                        float* __restrict__ wn, int* __restrict__ ctr) {
    int k = blockIdx.x * blockDim.x + threadIdx.x;   // 4 x 256 = 1024
    if (k == 0) ctr[0] = 0;
    if (k >= KCODES) return;
    float s = 0.f;
    unsigned short* row = WEg + (size_t)k * 128;
    #pragma unroll
    for (int d = 0; d < DIM; ++d) {
        float v = w[(size_t)k * DIM + d];
        s += v * v;
        unsigned short h = f2bf(v);
        row[d]      = h;
        row[64 + d] = f2bf(v - bf2f(h));
    }
    wn[k] = 0.5f * s;
}

// ---------------------------------------------------------------------------
// Main: 512 blocks x 256 thr (4 waves: 2 latent-halves x 2 code-halves).
// Wave tile 64 lats x 64 codes per 128-code chunk; A-frags (negated x) in
// registers; B-frags from global; barrier-free K-loop.
__global__ __launch_bounds__(256, 2)
void vq_main(const float* __restrict__ x, const float* __restrict__ w,
             const unsigned short* __restrict__ WEg, const float* __restrict__ wn,
             float* __restrict__ out, int* __restrict__ ctr, int* __restrict__ list) {
    __shared__ __align__(16) char smem[35840];
    unsigned short* XE = (unsigned short*)smem;        // [128][136] (phase 0 only)
    int*   bfin  = (int*)(smem + 34816);               // [128]
    float* b1fin = (float*)(smem + 35328);             // [128]
    float* red_b1 = (float*)smem;                      // [32][129] alias (post-K)
    int*   red_i1 = (int*)(smem + 16512);              // [32][129] alias

    const int tid  = threadIdx.x;
    const int wave = tid >> 6, lane = tid & 63;
    const int r16  = lane & 15, quad = lane >> 4;
    const int LH = wave & 1, CH = wave >> 1;

    const int blk = blockIdx.x;
    const int b   = blk >> 3;
    const int hw0 = (blk & 7) * LPB;

    // Phase 0: convert NEGATED x tile -> XE[lat][hi 0..63 | lo 64..127]
    {
        const int lat  = tid & 127;
        const int half = tid >> 7;
        const float* xb = x + (size_t)b * (DIM * HW) + hw0 + lat;
        #pragma unroll 8
        for (int c = 0; c < 32; ++c) {
            int chn = half * 32 + c;
            float v = -xb[chn * HW];          // negate: score = wn + (-x).w
            unsigned short h = f2bf(v);
            XE[lat * XROW + chn]      = h;
            XE[lat * XROW + 64 + chn] = f2bf(v - bf2f(h));
        }
    }
    __syncthreads();

    // A-frags: p0=hi ch0-31, p1=hi ch32-63, p2=lo ch0-31, p3=lo ch32-63
    short8 areg[4][4];
    #pragma unroll
    for (int lt = 0; lt < 4; ++lt)
        #pragma unroll
        for (int p = 0; p < 4; ++p)
            areg[lt][p] = *(const short8*)&XE[(LH * 64 + lt * 16 + r16) * XROW + p * 32 + quad * 8];
    __syncthreads();   // all areg loads done -> XE region reusable by epilogue

    float b1[16], b2[16]; int i1[16];
    #pragma unroll
    for (int sl = 0; sl < 16; ++sl) { b1[sl] = FLT_MAX; b2[sl] = FLT_MAX; i1[sl] = 0; }

    // Lane's B base: code row (CH*64 + ct*16 + r16), 16B seg (ws*4 + quad)
    const unsigned short* Wbase = WEg + (size_t)(CH * 64 + r16) * 128 + quad * 8;

    #pragma unroll 2
    for (int ch = 0; ch < 8; ++ch) {
        const int kb = ch * 128;
        float wnv[4]; int kk[4];
        #pragma unroll
        for (int ct = 0; ct < 4; ++ct) {
            kk[ct]  = kb + CH * 64 + ct * 16 + r16;
            wnv[ct] = wn[kk[ct]];
        }
        f32x4 acc[4][4];
        #pragma unroll
        for (int lt = 0; lt < 4; ++lt)
            #pragma unroll
            for (int ct = 0; ct < 4; ++ct) {
                acc[lt][ct][0] = wnv[ct]; acc[lt][ct][1] = wnv[ct];
                acc[lt][ct][2] = wnv[ct]; acc[lt][ct][3] = wnv[ct];
            }

        // K=192: (A span, W span): spans 0=hi0,1=hi1,2=lo0,3=lo1
        const int AI[6] = {0, 1, 0, 1, 2, 3};
        const int WS[6] = {0, 1, 2, 3, 0, 1};
        #pragma unroll
        for (int s = 0; s < 6; ++s) {
            short8 bf[4];
            #pragma unroll
            for (int ct = 0; ct < 4; ++ct)
                bf[ct] = *(const short8*)(Wbase + (size_t)(kb + ct * 16) * 128 + WS[s] * 32);
            #pragma unroll
            for (int lt = 0; lt < 4; ++lt)
                #pragma unroll
                for (int ct = 0; ct < 4; ++ct)
                    acc[lt][ct] = __builtin_amdgcn_mfma_f32_16x16x32_bf16(
                        areg[lt][AI[s]], bf[ct], acc[lt][ct], 0, 0, 0);
        }

        // Fold (5 VALU/score): per-thread k strictly ascending -> strict <
        #pragma unroll
        for (int ct = 0; ct < 4; ++ct)
            #pragma unroll
            for (int lt = 0; lt < 4; ++lt)
                #pragma unroll
                for (int r = 0; r < 4; ++r) {
                    int sl = lt * 4 + r;
                    float sc = acc[lt][ct][r];
                    bool ltb = sc < b1[sl];
                    b2[sl] = fminf(b2[sl], fmaxf(sc, b1[sl]));
                    b1[sl] = fminf(b1[sl], sc);
                    i1[sl] = ltb ? kk[ct] : i1[sl];
                }
    }

    // ---- Epilogue: two-phase LDS reduction (32 contributors per latent) ----
    const int cid = CH * 16 + r16;
    #pragma unroll
    for (int lt = 0; lt < 4; ++lt)
        #pragma unroll
        for (int r = 0; r < 4; ++r) {
            int sl = lt * 4 + r;
            int lat = LH * 64 + lt * 16 + quad * 4 + r;
            red_b1[cid * 129 + lat] = b1[sl];
            red_i1[cid * 129 + lat] = i1[sl];
        }
    __syncthreads();
    if (tid < LPB) {
        float B1 = red_b1[tid]; int I1 = red_i1[tid];
        #pragma unroll 4
        for (int c = 1; c < 32; ++c) {
            float c1 = red_b1[c * 129 + tid];
            int   ci = red_i1[c * 129 + tid];
            if (c1 < B1 || (c1 == B1 && ci < I1)) { B1 = c1; I1 = ci; }
        }
        bfin[tid] = I1; b1fin[tid] = B1;
    }
    __syncthreads();
    // Phase 2: global 2nd-best = min over contributors of (winner? b2 : b1)
    #pragma unroll
    for (int lt = 0; lt < 4; ++lt)
        #pragma unroll
        for (int r = 0; r < 4; ++r) {
            int sl = lt * 4 + r;
            int lat = LH * 64 + lt * 16 + quad * 4 + r;
            red_b1[cid * 129 + lat] = (i1[sl] == bfin[lat]) ? b2[sl] : b1[sl];
        }
    __syncthreads();
    if (tid < LPB) {
        float B2 = red_b1[tid];
        #pragma unroll 4
        for (int c = 1; c < 32; ++c) B2 = fminf(B2, red_b1[c * 129 + tid]);
        if (B2 - b1fin[tid] < EPS) {
            int pos = atomicAdd(ctr, 1);
            if (pos < RESCUE_CAP) list[pos] = blk * LPB + tid;
        }
    }
    __syncthreads();

    // ---- Gather: out[n][:] = w[bfin][:]  (coalesced float4) ----
    float* outp = out + (size_t)blk * (LPB * DIM);
    #pragma unroll
    for (int r = 0; r < 8; ++r) {
        int idx = r * 256 + tid;
        int row = idx >> 4, seg = idx & 15;
        int code = bfin[row];
        *(float4*)&outp[idx * 4] = *(const float4*)&w[(size_t)code * DIM + seg * 4];
    }
}

// ---------------------------------------------------------------------------
// Rescue: one wave per ambiguous latent, exact fp32 full-K rescore.
__global__ __launch_bounds__(256, 1)
void vq_rescue(const float* __restrict__ x, const float* __restrict__ w,
               const float* __restrict__ wn, float* __restrict__ out,
               const int* __restrict__ ctr, const int* __restrict__ list) {
    int cnt = ctr[0]; if (cnt > RESCUE_CAP) cnt = RESCUE_CAP;
    int g = blockIdx.x * 4 + (threadIdx.x >> 6);
    if (g >= cnt) return;
    const int lane = threadIdx.x & 63;
    const int n = list[g];
    const int b = n >> 10, hw = n & 1023;
    const float* xp = x + (size_t)b * (DIM * HW) + hw;
    float xs[DIM];
    #pragma unroll
    for (int d = 0; d < DIM; ++d) xs[d] = xp[d * HW];
    float bb = FLT_MAX; int bi = 0;
    #pragma unroll 2
    for (int c = 0; c < 16; ++c) {
        int k = c * 64 + lane;
        const float4* wr = (const float4*)(w + (size_t)k * DIM);
        float a0 = 0.f, a1 = 0.f, a2 = 0.f, a3 = 0.f;
        #pragma unroll
        for (int j = 0; j < 16; ++j) {
            float4 v = wr[j];
            a0 += xs[4 * j]     * v.x;  a1 += xs[4 * j + 1] * v.y;
            a2 += xs[4 * j + 2] * v.z;  a3 += xs[4 * j + 3] * v.w;
        }
        float s = wn[k] - ((a0 + a1) + (a2 + a3));
        if (s < bb) { bb = s; bi = k; }
    }
    #pragma unroll
    for (int off = 32; off > 0; off >>= 1) {
        float ob = __shfl_down(bb, off);
        int   oi = __shfl_down(bi, off);
        if (ob < bb || (ob == bb && oi < bi)) { bb = ob; bi = oi; }
    }
    int kw = __shfl(bi, 0);
    out[(size_t)n * DIM + lane] = w[(size_t)kw * DIM + lane];
}

extern "C" void kernel_launch(void* const* d_in, const int* in_sizes, int n_in,
                              void* d_out, int out_size, void* d_ws, size_t ws_size,
                              hipStream_t stream) {
    const float* x = (const float*)d_in[0];
    const float* w = (const float*)d_in[1];
    float* out = (float*)d_out;
    unsigned short* WEg = (unsigned short*)d_ws;                  // 262144 B
    float* wn  = (float*)((char*)d_ws + 262144);                  // 4096 B
    int*   ctr = (int*)((char*)d_ws + 266240);                    // 16 B
    int*   list = (int*)((char*)d_ws + 266256);                   // 16384 B

    vq_prep<<<4, 256, 0, stream>>>(w, WEg, wn, ctr);
    vq_main<<<NLAT / LPB, 256, 0, stream>>>(x, w, WEg, wn, out, ctr, list);
    vq_rescue<<<RESCUE_CAP / 4, 256, 0, stream>>>(x, w, wn, out, ctr, list);
}

// Round 6
// 171.517 us; speedup vs baseline: 1.0484x; 1.0484x over previous
//
#include <hip/hip_runtime.h>
#include <float.h>

// VectorQuantizer: x [64,64,32,32] f32, weight [1024,64] f32
// out[n] = weight[argmin_k ||x_n - w_k||^2]
// score = 0.5||w||^2 + (-x).w via split-bf16 MFMA, K=192 (hi.hi + lo_x.hi_w +
// hi_x.lo_w). Argmin state = packed sortable u32 keys (score high bits | k),
// folding via v_min_u32 -> 32 regs instead of 48 (R5 spilled 52MB scratch).
// Quantization (<=1024 ULP) absorbed into dynamic rescue eps; ambiguous
// latents get exact fp32 rescore in vq_rescue.
#define NLAT   65536
#define KCODES 1024
#define DIM    64
#define HW     1024
#define LPB    128
#define XROW   136          // XE padded row (shorts): 272 B
#define RESCUE_CAP 8192

typedef float f32x4 __attribute__((ext_vector_type(4)));
typedef short short8 __attribute__((ext_vector_type(8)));

static __device__ __forceinline__ unsigned short f2bf(float f) {
    unsigned int u = __float_as_uint(f);
    return (unsigned short)((u + 0x7fffu + ((u >> 16) & 1u)) >> 16);   // RNE
}
static __device__ __forceinline__ float bf2f(unsigned short h) {
    return __uint_as_float(((unsigned int)h) << 16);
}
// float -> order-preserving uint, low 10 bits replaced by code index k
static __device__ __forceinline__ unsigned int packkey(float sc, int k) {
    unsigned int u = __float_as_uint(sc);
    unsigned int m = (unsigned int)((int)u >> 31) | 0x80000000u;
    return ((u ^ m) & 0xFFFFFC00u) | (unsigned int)k;
}
static __device__ __forceinline__ float unpackf(unsigned int key) {
    unsigned int u = (key & 0x80000000u) ? (key ^ 0x80000000u) : ~key;
    return __uint_as_float(u);
}

// ---------------------------------------------------------------------------
// Prep: WEg[k] = 128 shorts: [0..63]=hi(w[k][d]), [64..127]=lo. wn=0.5||w||^2.
__global__ void vq_prep(const float* __restrict__ w, unsigned short* __restrict__ WEg,
                        float* __restrict__ wn, int* __restrict__ ctr) {
    int k = blockIdx.x * blockDim.x + threadIdx.x;   // 4 x 256 = 1024
    if (k == 0) ctr[0] = 0;
    if (k >= KCODES) return;
    float s = 0.f;
    unsigned short* row = WEg + (size_t)k * 128;
    #pragma unroll
    for (int d = 0; d < DIM; ++d) {
        float v = w[(size_t)k * DIM + d];
        s += v * v;
        unsigned short h = f2bf(v);
        row[d]      = h;
        row[64 + d] = f2bf(v - bf2f(h));
    }
    wn[k] = 0.5f * s;
}

// ---------------------------------------------------------------------------
// Main: 512 blocks x 256 thr (2 latent-halves x 2 code-halves). Wave tile
// 64 lats x 64 codes per 128-code chunk; A-frags (negated x) pinned in regs;
// B-frags straight from global (L2-resident); barrier-free K-loop.
__global__ __launch_bounds__(256, 2)
void vq_main(const float* __restrict__ x, const float* __restrict__ w,
             const unsigned short* __restrict__ WEg, const float* __restrict__ wn,
             float* __restrict__ out, int* __restrict__ ctr, int* __restrict__ list) {
    __shared__ __align__(16) char smem[35840];
    unsigned short* XE = (unsigned short*)smem;        // [128][136] (phase 0 only)
    unsigned int* red  = (unsigned int*)smem;          // [32][129] alias (post-K)
    unsigned int* K1s  = (unsigned int*)(smem + 34816);// [128] winner keys
    int*          bfin = (int*)(smem + 35328);         // [128] winner indices

    const int tid  = threadIdx.x;
    const int wave = tid >> 6, lane = tid & 63;
    const int r16  = lane & 15, quad = lane >> 4;
    const int LH = wave & 1, CH = wave >> 1;

    const int blk = blockIdx.x;
    const int b   = blk >> 3;
    const int hw0 = (blk & 7) * LPB;

    // Phase 0: convert NEGATED x tile -> XE[lat][hi 0..63 | lo 64..127]
    {
        const int lat  = tid & 127;
        const int half = tid >> 7;
        const float* xb = x + (size_t)b * (DIM * HW) + hw0 + lat;
        #pragma unroll 8
        for (int c = 0; c < 32; ++c) {
            int chn = half * 32 + c;
            float v = -xb[chn * HW];          // negate: score = wn + (-x).w
            unsigned short h = f2bf(v);
            XE[lat * XROW + chn]      = h;
            XE[lat * XROW + 64 + chn] = f2bf(v - bf2f(h));
        }
    }
    __syncthreads();

    // A-frags: p0=hi ch0-31, p1=hi ch32-63, p2=lo ch0-31, p3=lo ch32-63
    short8 areg[4][4];
    #pragma unroll
    for (int lt = 0; lt < 4; ++lt)
        #pragma unroll
        for (int p = 0; p < 4; ++p)
            areg[lt][p] = *(const short8*)&XE[(LH * 64 + lt * 16 + r16) * XROW + p * 32 + quad * 8];
    __syncthreads();   // XE dead -> epilogue may alias

    unsigned int key1[16], key2[16];
    #pragma unroll
    for (int sl = 0; sl < 16; ++sl) { key1[sl] = 0xFFFFFFFFu; key2[sl] = 0xFFFFFFFFu; }

    const unsigned short* Wbase = WEg + (size_t)(CH * 64 + r16) * 128 + quad * 8;

    #pragma unroll 2
    for (int ch = 0; ch < 8; ++ch) {
        const int kb = ch * 128;
        float wnv[4]; int kk[4];
        #pragma unroll
        for (int ct = 0; ct < 4; ++ct) {
            kk[ct]  = kb + CH * 64 + ct * 16 + r16;
            wnv[ct] = wn[kk[ct]];
        }
        f32x4 acc[4][4];
        #pragma unroll
        for (int lt = 0; lt < 4; ++lt)
            #pragma unroll
            for (int ct = 0; ct < 4; ++ct) {
                acc[lt][ct][0] = wnv[ct]; acc[lt][ct][1] = wnv[ct];
                acc[lt][ct][2] = wnv[ct]; acc[lt][ct][3] = wnv[ct];
            }

        // K=192: (A span, W span); spans 0=hi0,1=hi1,2=lo0,3=lo1
        const int AI[6] = {0, 1, 0, 1, 2, 3};
        const int WS[6] = {0, 1, 2, 3, 0, 1};
        #pragma unroll
        for (int s = 0; s < 6; ++s) {
            short8 bf[4];
            #pragma unroll
            for (int ct = 0; ct < 4; ++ct)
                bf[ct] = *(const short8*)(Wbase + (size_t)(kb + ct * 16) * 128 + WS[s] * 32);
            #pragma unroll
            for (int lt = 0; lt < 4; ++lt)
                #pragma unroll
                for (int ct = 0; ct < 4; ++ct)
                    acc[lt][ct] = __builtin_amdgcn_mfma_f32_16x16x32_bf16(
                        areg[lt][AI[s]], bf[ct], acc[lt][ct], 0, 0, 0);
        }

        // Fold: pack + u32 min/duel (k in low bits -> first-occurrence ties)
        #pragma unroll
        for (int ct = 0; ct < 4; ++ct)
            #pragma unroll
            for (int lt = 0; lt < 4; ++lt)
                #pragma unroll
                for (int r = 0; r < 4; ++r) {
                    int sl = lt * 4 + r;
                    unsigned int key = packkey(acc[lt][ct][r], kk[ct]);
                    unsigned int hi  = key > key1[sl] ? key : key1[sl];
                    key2[sl] = key2[sl] < hi ? key2[sl] : hi;
                    key1[sl] = key1[sl] < key ? key1[sl] : key;
                }
    }

    // ---- Epilogue: u32-min LDS reduction (32 contributors per latent) ----
    const int cid = CH * 16 + r16;
    #pragma unroll
    for (int lt = 0; lt < 4; ++lt)
        #pragma unroll
        for (int r = 0; r < 4; ++r) {
            int lat = LH * 64 + lt * 16 + quad * 4 + r;
            red[cid * 129 + lat] = key1[lt * 4 + r];
        }
    __syncthreads();
    if (tid < LPB) {
        unsigned int B1 = red[tid];
        #pragma unroll 4
        for (int c = 1; c < 32; ++c) {
            unsigned int v = red[c * 129 + tid];
            B1 = v < B1 ? v : B1;
        }
        K1s[tid]  = B1;
        bfin[tid] = (int)(B1 & 1023u);
    }
    __syncthreads();
    // Phase 2: global 2nd best = min over (winner? key2 : key1)
    #pragma unroll
    for (int lt = 0; lt < 4; ++lt)
        #pragma unroll
        for (int r = 0; r < 4; ++r) {
            int sl = lt * 4 + r;
            int lat = LH * 64 + lt * 16 + quad * 4 + r;
            red[cid * 129 + lat] = (key1[sl] == K1s[lat]) ? key2[sl] : key1[sl];
        }
    __syncthreads();
    if (tid < LPB) {
        unsigned int B2 = red[tid];
        #pragma unroll 4
        for (int c = 1; c < 32; ++c) {
            unsigned int v = red[c * 129 + tid];
            B2 = v < B2 ? v : B2;
        }
        float f1 = unpackf(K1s[tid]), f2 = unpackf(B2);
        float eps = 2.0e-3f + 6.0e-4f * fabsf(f1);   // mfma err + 2x 1024-ULP quant
        if (f2 - f1 < eps) {
            int pos = atomicAdd(ctr, 1);
            if (pos < RESCUE_CAP) list[pos] = blk * LPB + tid;
        }
    }
    __syncthreads();

    // ---- Gather: out[n][:] = w[bfin][:]  (coalesced float4) ----
    float* outp = out + (size_t)blk * (LPB * DIM);
    #pragma unroll
    for (int r = 0; r < 8; ++r) {
        int idx = r * 256 + tid;
        int row = idx >> 4, seg = idx & 15;
        int code = bfin[row];
        *(float4*)&outp[idx * 4] = *(const float4*)&w[(size_t)code * DIM + seg * 4];
    }
}

// ---------------------------------------------------------------------------
// Rescue: one wave per ambiguous latent, exact fp32 full-K rescore.
__global__ __launch_bounds__(256, 1)
void vq_rescue(const float* __restrict__ x, const float* __restrict__ w,
               const float* __restrict__ wn, float* __restrict__ out,
               const int* __restrict__ ctr, const int* __restrict__ list) {
    int cnt = ctr[0]; if (cnt > RESCUE_CAP) cnt = RESCUE_CAP;
    int g = blockIdx.x * 4 + (threadIdx.x >> 6);
    if (g >= cnt) return;
    const int lane = threadIdx.x & 63;
    const int n = list[g];
    const int b = n >> 10, hw = n & 1023;
    const float* xp = x + (size_t)b * (DIM * HW) + hw;
    float xs[DIM];
    #pragma unroll
    for (int d = 0; d < DIM; ++d) xs[d] = xp[d * HW];
    float bb = FLT_MAX; int bi = 0;
    #pragma unroll 2
    for (int c = 0; c < 16; ++c) {
        int k = c * 64 + lane;
        const float4* wr = (const float4*)(w + (size_t)k * DIM);
        float a0 = 0.f, a1 = 0.f, a2 = 0.f, a3 = 0.f;
        #pragma unroll
        for (int j = 0; j < 16; ++j) {
            float4 v = wr[j];
            a0 += xs[4 * j]     * v.x;  a1 += xs[4 * j + 1] * v.y;
            a2 += xs[4 * j + 2] * v.z;  a3 += xs[4 * j + 3] * v.w;
        }
        float s = wn[k] - ((a0 + a1) + (a2 + a3));
        if (s < bb) { bb = s; bi = k; }
    }
    #pragma unroll
    for (int off = 32; off > 0; off >>= 1) {
        float ob = __shfl_down(bb, off);
        int   oi = __shfl_down(bi, off);
        if (ob < bb || (ob == bb && oi < bi)) { bb = ob; bi = oi; }
    }
    int kw = __shfl(bi, 0);
    out[(size_t)n * DIM + lane] = w[(size_t)kw * DIM + lane];
}

extern "C" void kernel_launch(void* const* d_in, const int* in_sizes, int n_in,
                              void* d_out, int out_size, void* d_ws, size_t ws_size,
                              hipStream_t stream) {
    const float* x = (const float*)d_in[0];
    const float* w = (const float*)d_in[1];
    float* out = (float*)d_out;
    unsigned short* WEg = (unsigned short*)d_ws;                  // 262144 B
    float* wn  = (float*)((char*)d_ws + 262144);                  // 4096 B
    int*   ctr = (int*)((char*)d_ws + 266240);                    // 16 B
    int*   list = (int*)((char*)d_ws + 266256);                   // 32768 B

    vq_prep<<<4, 256, 0, stream>>>(w, WEg, wn, ctr);
    vq_main<<<NLAT / LPB, 256, 0, stream>>>(x, w, WEg, wn, out, ctr, list);
    vq_rescue<<<RESCUE_CAP / 4, 256, 0, stream>>>(x, w, wn, out, ctr, list);
}

// Round 8
// 139.844 us; speedup vs baseline: 1.2859x; 1.2265x over previous
//
#include <hip/hip_runtime.h>
#include <float.h>

// VectorQuantizer: x [64,64,32,32] f32, weight [1024,64] f32
// out[n] = weight[argmin_k ||x_n - w_k||^2]
// score = 0.5||w||^2 + (-x).w via split-bf16 MFMA, K=192. B staged in LDS via
// global_load_lds double-buffer (prefetch issued at loop-top = one compute
// phase ahead of its barrier -> no vmcnt drain stall). Global-B (R5/R6)
// spilled 48MB scratch from hoisted loads -> back to LDS (R3/R4 = no spill).
// Fold: k embedded in score's low 10 mantissa bits (1 v_and_or_b32) + float
// min/duel = 4 VALU/score. Truncation/mfma error covered by dynamic-eps
// exact-fp32 rescue.
// NOTE: no pointer ARRAYS into LDS (addrspacecast static-init fails on
// gfx950) -- use scalar pointers + ternary select.
#define NLAT   65536
#define KCODES 1024
#define DIM    64
#define HW     1024
#define LPB    128
#define XROW   136          // XE padded row (shorts): 272 B
#define RESCUE_CAP 8192

typedef float f32x4 __attribute__((ext_vector_type(4)));
typedef short short8 __attribute__((ext_vector_type(8)));

static __device__ __forceinline__ unsigned short f2bf(float f) {
    unsigned int u = __float_as_uint(f);
    return (unsigned short)((u + 0x7fffu + ((u >> 16) & 1u)) >> 16);   // RNE
}
static __device__ __forceinline__ float bf2f(unsigned short h) {
    return __uint_as_float(((unsigned int)h) << 16);
}
static __device__ __forceinline__ void async_cp16(const void* g, void* l) {
    __builtin_amdgcn_global_load_lds(
        (const __attribute__((address_space(1))) unsigned int*)g,
        (__attribute__((address_space(3))) unsigned int*)l, 16, 0, 0);
}

// ---------------------------------------------------------------------------
// Prep: WEg[k] = 256B row of 16 swizzled 16B segs. Logical seg L: L<8 ->
// hi(d=8L..8L+7), L>=8 -> lo(d=8(L-8)..). Physical pos = L ^ (k & 15) so the
// byte-linear DMA lands bank-conflict-free for the MFMA read pattern.
__global__ void vq_prep(const float* __restrict__ w, unsigned short* __restrict__ WEg,
                        float* __restrict__ wn, int* __restrict__ ctr) {
    int k = blockIdx.x * blockDim.x + threadIdx.x;   // 4 x 256 = 1024
    if (k == 0) ctr[0] = 0;
    if (k >= KCODES) return;
    float s = 0.f;
    #pragma unroll
    for (int d = 0; d < DIM; ++d) { float v = w[(size_t)k * DIM + d]; s += v * v; }
    wn[k] = 0.5f * s;
    unsigned short* row = WEg + (size_t)k * 128;
    #pragma unroll
    for (int L = 0; L < 16; ++L) {
        short8 seg;
        #pragma unroll
        for (int j = 0; j < 8; ++j) {
            float v = w[(size_t)k * DIM + (L & 7) * 8 + j];
            unsigned short h = f2bf(v);
            seg[j] = (L < 8) ? (short)h : (short)f2bf(v - bf2f(h));
        }
        *(short8*)(row + ((L ^ (k & 15)) << 3)) = seg;
    }
}

// ---------------------------------------------------------------------------
// Main: 512 blocks x 256 thr (2 latent-halves x 2 code-halves). Wave tile
// 64 lats x 64 codes per 128-code chunk; A-frags (negated x) pinned in regs;
// B double-buffered in LDS via async DMA.
__global__ __launch_bounds__(256, 2)
void vq_main(const float* __restrict__ x, const float* __restrict__ w,
             const unsigned short* __restrict__ WEg, const float* __restrict__ wn,
             float* __restrict__ out, int* __restrict__ ctr, int* __restrict__ list) {
    __shared__ __align__(16) char smem[66560];
    unsigned short* XE = (unsigned short*)smem;        // [128][136] (phase 0; dies
                                                       //  before wbuf use)
    char* wbuf0 = smem;                                // 32KB B buffer (even chunks)
    char* wbuf1 = smem + 32768;                        // 32KB B buffer (odd chunks)
    unsigned int* red = (unsigned int*)smem;           // [32][129] epilogue alias
    unsigned int* K1s = (unsigned int*)(smem + 65536); // [128] winner bits
    int*         bfin = (int*)(smem + 66048);          // [128] winner indices

    const int tid  = threadIdx.x;
    const int wave = tid >> 6, lane = tid & 63;
    const int r16  = lane & 15, quad = lane >> 4;
    const int LH = wave & 1, CH = wave >> 1;

    const int blk = blockIdx.x;
    const int b   = blk >> 3;
    const int hw0 = (blk & 7) * LPB;

    // Phase 0: convert NEGATED x tile -> XE[lat][hi 0..63 | lo 64..127]
    {
        const int lat  = tid & 127;
        const int half = tid >> 7;
        const float* xb = x + (size_t)b * (DIM * HW) + hw0 + lat;
        #pragma unroll 8
        for (int c = 0; c < 32; ++c) {
            int chn = half * 32 + c;
            float v = -xb[chn * HW];          // negate: score = wn + (-x).w
            unsigned short h = f2bf(v);
            XE[lat * XROW + chn]      = h;
            XE[lat * XROW + 64 + chn] = f2bf(v - bf2f(h));
        }
    }
    __syncthreads();

    // A-frags: span 0=hi d0-31, 1=hi d32-63, 2=lo d0-31, 3=lo d32-63
    short8 areg[4][4];
    #pragma unroll
    for (int lt = 0; lt < 4; ++lt)
        #pragma unroll
        for (int p = 0; p < 4; ++p)
            areg[lt][p] = *(const short8*)&XE[(LH * 64 + lt * 16 + r16) * XROW + p * 32 + quad * 8];
    __syncthreads();   // XE dead -> wbuf/red may overwrite

    // Prefetch chunk 0 into wbuf0 (drained by the first loop-top barrier)
    {
        const char* gsrc = (const char*)WEg + wave * 8192 + lane * 16;
        char* ldst = wbuf0 + wave * 8192;
        #pragma unroll
        for (int i = 0; i < 8; ++i) async_cp16(gsrc + i * 1024, ldst + i * 1024);
    }

    float b1[16], b2[16];
    #pragma unroll
    for (int sl = 0; sl < 16; ++sl) { b1[sl] = FLT_MAX; b2[sl] = FLT_MAX; }

    for (int ch = 0; ch < 8; ++ch) {
        __syncthreads();   // drains chunk-ch DMA (issued one full phase ago)
        if (ch + 1 < 8) {  // prefetch next chunk; its barrier is a phase away
            const char* gsrc = (const char*)WEg + (ch + 1) * 32768 + wave * 8192 + lane * 16;
            char* ldst = (((ch + 1) & 1) ? wbuf1 : wbuf0) + wave * 8192;
            #pragma unroll
            for (int i = 0; i < 8; ++i) async_cp16(gsrc + i * 1024, ldst + i * 1024);
        }
        const char* cbuf = (ch & 1) ? wbuf1 : wbuf0;
        const int kb = ch * 128;

        float wnv[4]; int kk[4];
        #pragma unroll
        for (int ct = 0; ct < 4; ++ct) {
            kk[ct]  = kb + CH * 64 + ct * 16 + r16;
            wnv[ct] = wn[kk[ct]];
        }
        f32x4 acc[4][4];
        #pragma unroll
        for (int lt = 0; lt < 4; ++lt)
            #pragma unroll
            for (int ct = 0; ct < 4; ++ct) {
                acc[lt][ct][0] = wnv[ct]; acc[lt][ct][1] = wnv[ct];
                acc[lt][ct][2] = wnv[ct]; acc[lt][ct][3] = wnv[ct];
            }

        // K=192, W-span loaded once each: (A0,W0)(A2,W0)(A1,W1)(A3,W1)(A0,W2)(A1,W3)
        const int AI[6] = {0, 2, 1, 3, 0, 1};
        const int WSp[6] = {0, 0, 1, 1, 2, 3};
        short8 bf[4];
        #pragma unroll
        for (int s = 0; s < 6; ++s) {
            if (s == 0 || WSp[s] != WSp[s - 1]) {
                #pragma unroll
                for (int ct = 0; ct < 4; ++ct) {
                    int r = CH * 64 + ct * 16 + r16;
                    int seg = (WSp[s] * 4 + quad) ^ r16;   // matches prep swizzle
                    bf[ct] = *(const short8*)(cbuf + r * 256 + seg * 16);
                }
            }
            #pragma unroll
            for (int lt = 0; lt < 4; ++lt)
                #pragma unroll
                for (int ct = 0; ct < 4; ++ct)
                    acc[lt][ct] = __builtin_amdgcn_mfma_f32_16x16x32_bf16(
                        areg[lt][AI[s]], bf[ct], acc[lt][ct], 0, 0, 0);
        }

        // Fold: embed k in low 10 mantissa bits (1 op) + min/duel (3 ops)
        #pragma unroll
        for (int ct = 0; ct < 4; ++ct)
            #pragma unroll
            for (int lt = 0; lt < 4; ++lt)
                #pragma unroll
                for (int r = 0; r < 4; ++r) {
                    int sl = lt * 4 + r;
                    float p = __uint_as_float(
                        (__float_as_uint(acc[lt][ct][r]) & 0xFFFFFC00u) | (unsigned)kk[ct]);
                    float t = fmaxf(p, b1[sl]);
                    b2[sl] = fminf(b2[sl], t);
                    b1[sl] = fminf(b1[sl], p);
                }
    }

    // ---- Epilogue: float-min LDS reduction (32 contributors per latent) ----
    __syncthreads();   // wbuf dead -> red alias safe
    const int cid = CH * 16 + r16;
    #pragma unroll
    for (int lt = 0; lt < 4; ++lt)
        #pragma unroll
        for (int r = 0; r < 4; ++r) {
            int lat = LH * 64 + lt * 16 + quad * 4 + r;
            ((float*)red)[cid * 129 + lat] = b1[lt * 4 + r];
        }
    __syncthreads();
    if (tid < LPB) {
        float B1 = ((float*)red)[tid];
        #pragma unroll 4
        for (int c = 1; c < 32; ++c)
            B1 = fminf(B1, ((float*)red)[c * 129 + tid]);
        K1s[tid]  = __float_as_uint(B1);
        bfin[tid] = (int)(__float_as_uint(B1) & 1023u);
    }
    __syncthreads();
    // Phase 2: global 2nd best = min over (winner-holder? b2 : b1)
    #pragma unroll
    for (int lt = 0; lt < 4; ++lt)
        #pragma unroll
        for (int r = 0; r < 4; ++r) {
            int sl = lt * 4 + r;
            int lat = LH * 64 + lt * 16 + quad * 4 + r;
            bool isw = (__float_as_uint(b1[sl]) == K1s[lat]);
            ((float*)red)[cid * 129 + lat] = isw ? b2[sl] : b1[sl];
        }
    __syncthreads();
    if (tid < LPB) {
        float f2 = ((float*)red)[tid];
        #pragma unroll 4
        for (int c = 1; c < 32; ++c)
            f2 = fminf(f2, ((float*)red)[c * 129 + tid]);
        float f1 = __uint_as_float(K1s[tid]);
        float eps = 2.0e-3f + 6.0e-4f * fabsf(f1);   // mfma err + index-embed quant
        if (f2 - f1 < eps) {
            int pos = atomicAdd(ctr, 1);
            if (pos < RESCUE_CAP) list[pos] = blk * LPB + tid;
        }
    }
    __syncthreads();

    // ---- Gather: out[n][:] = w[bfin][:]  (coalesced float4) ----
    float* outp = out + (size_t)blk * (LPB * DIM);
    #pragma unroll
    for (int r = 0; r < 8; ++r) {
        int idx = r * 256 + tid;
        int row = idx >> 4, seg = idx & 15;
        int code = bfin[row];
        *(float4*)&outp[idx * 4] = *(const float4*)&w[(size_t)code * DIM + seg * 4];
    }
}

// ---------------------------------------------------------------------------
// Rescue: one wave per ambiguous latent, exact fp32 full-K rescore.
__global__ __launch_bounds__(256, 1)
void vq_rescue(const float* __restrict__ x, const float* __restrict__ w,
               const float* __restrict__ wn, float* __restrict__ out,
               const int* __restrict__ ctr, const int* __restrict__ list) {
    int cnt = ctr[0]; if (cnt > RESCUE_CAP) cnt = RESCUE_CAP;
    int g = blockIdx.x * 4 + (threadIdx.x >> 6);
    if (g >= cnt) return;
    const int lane = threadIdx.x & 63;
    const int n = list[g];
    const int b = n >> 10, hw = n & 1023;
    const float* xp = x + (size_t)b * (DIM * HW) + hw;
    float xs[DIM];
    #pragma unroll
    for (int d = 0; d < DIM; ++d) xs[d] = xp[d * HW];
    float bb = FLT_MAX; int bi = 0;
    #pragma unroll 2
    for (int c = 0; c < 16; ++c) {
        int k = c * 64 + lane;
        const float4* wr = (const float4*)(w + (size_t)k * DIM);
        float a0 = 0.f, a1 = 0.f, a2 = 0.f, a3 = 0.f;
        #pragma unroll
        for (int j = 0; j < 16; ++j) {
            float4 v = wr[j];
            a0 += xs[4 * j]     * v.x;  a1 += xs[4 * j + 1] * v.y;
            a2 += xs[4 * j + 2] * v.z;  a3 += xs[4 * j + 3] * v.w;
        }
        float s = wn[k] - ((a0 + a1) + (a2 + a3));
        if (s < bb) { bb = s; bi = k; }
    }
    #pragma unroll
    for (int off = 32; off > 0; off >>= 1) {
        float ob = __shfl_down(bb, off);
        int   oi = __shfl_down(bi, off);
        if (ob < bb || (ob == bb && oi < bi)) { bb = ob; bi = oi; }
    }
    int kw = __shfl(bi, 0);
    out[(size_t)n * DIM + lane] = w[(size_t)kw * DIM + lane];
}

extern "C" void kernel_launch(void* const* d_in, const int* in_sizes, int n_in,
                              void* d_out, int out_size, void* d_ws, size_t ws_size,
                              hipStream_t stream) {
    const float* x = (const float*)d_in[0];
    const float* w = (const float*)d_in[1];
    float* out = (float*)d_out;
    unsigned short* WEg = (unsigned short*)d_ws;                  // 262144 B (swizzled)
    float* wn  = (float*)((char*)d_ws + 262144);                  // 4096 B
    int*   ctr = (int*)((char*)d_ws + 266240);                    // 16 B
    int*   list = (int*)((char*)d_ws + 266256);                   // 32768 B

    vq_prep<<<4, 256, 0, stream>>>(w, WEg, wn, ctr);
    vq_main<<<NLAT / LPB, 256, 0, stream>>>(x, w, WEg, wn, out, ctr, list);
    vq_rescue<<<RESCUE_CAP / 4, 256, 0, stream>>>(x, w, wn, out, ctr, list);
}

// Round 9
// 122.133 us; speedup vs baseline: 1.4723x; 1.1450x over previous
//
#include <hip/hip_runtime.h>
#include <float.h>

// VectorQuantizer: x [64,64,32,32] f32, weight [1024,64] f32
// out[n] = weight[argmin_k ||x_n - w_k||^2]
// score = 0.5||w||^2 + (-x).w via split-bf16 MFMA, K=192 (hi.hi + lo.hi + hi.lo).
// B staged in LDS via global_load_lds double-buffer (prefetch one compute phase
// ahead of its consuming barrier). Fold embeds only 5 bits (vid = ch*4+ct; CH,
// r16 are thread-constants) in the score's low mantissa -> truncation 2^-19 rel,
// full k reconstructed in epilogue; cross-thread reduce is exact lexicographic
// (score,k). Ambiguous latents (top-2 margin < eps) rescored exactly INLINE by
// the block's waves (no 3rd launch, no global ctr/list).
// NOTE: no pointer ARRAYS into LDS (addrspacecast static-init fails on gfx950).
#define NLAT   65536
#define KCODES 1024
#define DIM    64
#define HW     1024
#define LPB    128
#define XROW   136          // XE padded row (shorts): 272 B

typedef float f32x4 __attribute__((ext_vector_type(4)));
typedef short short8 __attribute__((ext_vector_type(8)));

static __device__ __forceinline__ unsigned short f2bf(float f) {
    unsigned int u = __float_as_uint(f);
    return (unsigned short)((u + 0x7fffu + ((u >> 16) & 1u)) >> 16);   // RNE
}
static __device__ __forceinline__ float bf2f(unsigned short h) {
    return __uint_as_float(((unsigned int)h) << 16);
}
static __device__ __forceinline__ void async_cp16(const void* g, void* l) {
    __builtin_amdgcn_global_load_lds(
        (const __attribute__((address_space(1))) unsigned int*)g,
        (__attribute__((address_space(3))) unsigned int*)l, 16, 0, 0);
}

// ---------------------------------------------------------------------------
// Prep: WEg[k] = 256B row of 16 swizzled 16B segs. Logical seg L: L<8 ->
// hi(d=8L..8L+7), L>=8 -> lo. Physical pos = L ^ (k & 15) (bank swizzle baked
// into global so the byte-linear DMA lands conflict-free for the MFMA reads).
__global__ void vq_prep(const float* __restrict__ w, unsigned short* __restrict__ WEg,
                        float* __restrict__ wn) {
    int k = blockIdx.x * blockDim.x + threadIdx.x;   // 4 x 256 = 1024
    if (k >= KCODES) return;
    float s = 0.f;
    #pragma unroll
    for (int d = 0; d < DIM; ++d) { float v = w[(size_t)k * DIM + d]; s += v * v; }
    wn[k] = 0.5f * s;
    unsigned short* row = WEg + (size_t)k * 128;
    #pragma unroll
    for (int L = 0; L < 16; ++L) {
        short8 seg;
        #pragma unroll
        for (int j = 0; j < 8; ++j) {
            float v = w[(size_t)k * DIM + (L & 7) * 8 + j];
            unsigned short h = f2bf(v);
            seg[j] = (L < 8) ? (short)h : (short)f2bf(v - bf2f(h));
        }
        *(short8*)(row + ((L ^ (k & 15)) << 3)) = seg;
    }
}

// ---------------------------------------------------------------------------
// Main: 512 blocks x 256 thr (2 latent-halves x 2 code-halves). Wave tile
// 64 lats x 64 codes per 128-code chunk; A-frags (negated x) pinned in regs;
// B double-buffered in LDS via async DMA; inline exact rescue; gather.
__global__ __launch_bounds__(256, 2)
void vq_main(const float* __restrict__ x, const float* __restrict__ w,
             const unsigned short* __restrict__ WEg, const float* __restrict__ wn,
             float* __restrict__ out) {
    __shared__ __align__(16) char smem[66576];
    unsigned short* XE = (unsigned short*)smem;        // [128][136] (phase 0 only)
    char* wbuf0 = smem;                                // 32KB B buf (even chunks)
    char* wbuf1 = smem + 32768;                        // 32KB B buf (odd chunks)
    float* red  = (float*)smem;                        // [32][129] f32 (post-K)
    int*   redk = (int*)(smem + 16512);                // [32][129] int (post-K)
    int*   bfin = (int*)(smem + 65536);                // [128] winner k
    int*   amb  = (int*)(smem + 66048);                // [128] ambiguous lat ids
    int*   ambn = (int*)(smem + 66560);                // count

    const int tid  = threadIdx.x;
    const int wave = tid >> 6, lane = tid & 63;
    const int r16  = lane & 15, quad = lane >> 4;
    const int LH = wave & 1, CH = wave >> 1;

    const int blk = blockIdx.x;
    const int b   = blk >> 3;
    const int hw0 = (blk & 7) * LPB;

    if (tid == 0) ambn[0] = 0;

    // Phase 0: convert NEGATED x tile -> XE[lat][hi 0..63 | lo 64..127]
    {
        const int lat  = tid & 127;
        const int half = tid >> 7;
        const float* xb = x + (size_t)b * (DIM * HW) + hw0 + lat;
        #pragma unroll 8
        for (int c = 0; c < 32; ++c) {
            int chn = half * 32 + c;
            float v = -xb[chn * HW];          // negate: score = wn + (-x).w
            unsigned short h = f2bf(v);
            XE[lat * XROW + chn]      = h;
            XE[lat * XROW + 64 + chn] = f2bf(v - bf2f(h));
        }
    }
    __syncthreads();

    // A-frags: span 0=hi d0-31, 1=hi d32-63, 2=lo d0-31, 3=lo d32-63
    short8 areg[4][4];
    #pragma unroll
    for (int lt = 0; lt < 4; ++lt)
        #pragma unroll
        for (int p = 0; p < 4; ++p)
            areg[lt][p] = *(const short8*)&XE[(LH * 64 + lt * 16 + r16) * XROW + p * 32 + quad * 8];
    __syncthreads();   // XE dead -> wbuf may overwrite

    // Prefetch chunk 0 into wbuf0 (drained by the first loop-top barrier)
    {
        const char* gsrc = (const char*)WEg + wave * 8192 + lane * 16;
        char* ldst = wbuf0 + wave * 8192;
        #pragma unroll
        for (int i = 0; i < 8; ++i) async_cp16(gsrc + i * 1024, ldst + i * 1024);
    }

    float b1[16], b2[16];
    #pragma unroll
    for (int sl = 0; sl < 16; ++sl) { b1[sl] = FLT_MAX; b2[sl] = FLT_MAX; }

    for (int ch = 0; ch < 8; ++ch) {
        __syncthreads();   // drains chunk-ch DMA (issued one full phase ago)
        if (ch + 1 < 8) {  // prefetch next chunk; its barrier is a phase away
            const char* gsrc = (const char*)WEg + (ch + 1) * 32768 + wave * 8192 + lane * 16;
            char* ldst = (((ch + 1) & 1) ? wbuf1 : wbuf0) + wave * 8192;
            #pragma unroll
            for (int i = 0; i < 8; ++i) async_cp16(gsrc + i * 1024, ldst + i * 1024);
        }
        const char* cbuf = (ch & 1) ? wbuf1 : wbuf0;
        const int kb = ch * 128;

        float wnv[4];
        #pragma unroll
        for (int ct = 0; ct < 4; ++ct)
            wnv[ct] = wn[kb + CH * 64 + ct * 16 + r16];
        f32x4 acc[4][4];
        #pragma unroll
        for (int lt = 0; lt < 4; ++lt)
            #pragma unroll
            for (int ct = 0; ct < 4; ++ct) {
                acc[lt][ct][0] = wnv[ct]; acc[lt][ct][1] = wnv[ct];
                acc[lt][ct][2] = wnv[ct]; acc[lt][ct][3] = wnv[ct];
            }

        // K=192, W-span loaded once each: (A0,W0)(A2,W0)(A1,W1)(A3,W1)(A0,W2)(A1,W3)
        const int AI[6] = {0, 2, 1, 3, 0, 1};
        const int WSp[6] = {0, 0, 1, 1, 2, 3};
        short8 bf[4];
        #pragma unroll
        for (int s = 0; s < 6; ++s) {
            if (s == 0 || WSp[s] != WSp[s - 1]) {
                #pragma unroll
                for (int ct = 0; ct < 4; ++ct) {
                    int r = CH * 64 + ct * 16 + r16;
                    int seg = (WSp[s] * 4 + quad) ^ r16;   // matches prep swizzle
                    bf[ct] = *(const short8*)(cbuf + r * 256 + seg * 16);
                }
            }
            #pragma unroll
            for (int lt = 0; lt < 4; ++lt)
                #pragma unroll
                for (int ct = 0; ct < 4; ++ct)
                    acc[lt][ct] = __builtin_amdgcn_mfma_f32_16x16x32_bf16(
                        areg[lt][AI[s]], bf[ct], acc[lt][ct], 0, 0, 0);
        }

        // Fold: embed vid=(ch<<2)|ct in low 5 mantissa bits (1 v_and_or_b32),
        // then min/duel (3 ops). vid ascending == k ascending per slot.
        #pragma unroll
        for (int ct = 0; ct < 4; ++ct) {
            const unsigned vid = (unsigned)((ch << 2) | ct);
            #pragma unroll
            for (int lt = 0; lt < 4; ++lt)
                #pragma unroll
                for (int r = 0; r < 4; ++r) {
                    int sl = lt * 4 + r;
                    float p = __uint_as_float(
                        (__float_as_uint(acc[lt][ct][r]) & 0xFFFFFFE0u) | vid);
                    float t = fmaxf(p, b1[sl]);
                    b2[sl] = fminf(b2[sl], t);
                    b1[sl] = fminf(b1[sl], p);
                }
        }
    }

    // ---- Epilogue phase 1: exact lexicographic (score,k) reduction ----
    __syncthreads();   // wbuf dead -> red/redk alias safe
    const int cid = CH * 16 + r16;
    int kslot[16];
    #pragma unroll
    for (int lt = 0; lt < 4; ++lt)
        #pragma unroll
        for (int r = 0; r < 4; ++r) {
            int sl = lt * 4 + r;
            unsigned ub = __float_as_uint(b1[sl]);
            int vid = (int)(ub & 31u);
            int k = (vid >> 2) * 128 + CH * 64 + (vid & 3) * 16 + r16;
            kslot[sl] = k;
            int lat = LH * 64 + lt * 16 + quad * 4 + r;
            red[cid * 129 + lat]  = __uint_as_float(ub & 0xFFFFFFE0u);
            redk[cid * 129 + lat] = k;
        }
    __syncthreads();
    float B1 = 0.f;        // kept live across phases by the tid<LPB thread
    if (tid < LPB) {
        B1 = red[tid]; int I1 = redk[tid];
        #pragma unroll 4
        for (int c = 1; c < 32; ++c) {
            float s = red[c * 129 + tid]; int k2 = redk[c * 129 + tid];
            if (s < B1 || (s == B1 && k2 < I1)) { B1 = s; I1 = k2; }
        }
        bfin[tid] = I1;
    }
    __syncthreads();
    // Phase 2: global 2nd best = min over (holder-of-winner-k ? b2 : b1)
    #pragma unroll
    for (int lt = 0; lt < 4; ++lt)
        #pragma unroll
        for (int r = 0; r < 4; ++r) {
            int sl = lt * 4 + r;
            int lat = LH * 64 + lt * 16 + quad * 4 + r;
            float b1c = __uint_as_float(__float_as_uint(b1[sl]) & 0xFFFFFFE0u);
            float b2c = __uint_as_float(__float_as_uint(b2[sl]) & 0xFFFFFFE0u);
            red[cid * 129 + lat] = (kslot[sl] == bfin[lat]) ? b2c : b1c;
        }
    __syncthreads();
    if (tid < LPB) {
        float f2 = red[tid];
        #pragma unroll 4
        for (int c = 1; c < 32; ++c) f2 = fminf(f2, red[c * 129 + tid]);
        // eps: split residual + dropped lo.lo + fp32 accum + 2x 5-bit truncation
        float eps = 1.0e-3f + 6.0e-5f * fabsf(B1);
        if (f2 - B1 < eps) {
            int pos = atomicAdd(ambn, 1);
            amb[pos] = tid;
        }
    }
    __syncthreads();

    // ---- Inline exact rescue: one wave per ambiguous latent ----
    {
        const int na = ambn[0];
        for (int e = wave; e < na; e += 4) {
            const int lat = amb[e];
            const float* xp = x + (size_t)b * (DIM * HW) + hw0 + lat;
            float xs[DIM];
            #pragma unroll
            for (int d = 0; d < DIM; ++d) xs[d] = xp[d * HW];  // wave-uniform
            float bb = FLT_MAX; int bi = 0;
            #pragma unroll 2
            for (int c = 0; c < 16; ++c) {
                int k = c * 64 + lane;
                const float4* wr = (const float4*)(w + (size_t)k * DIM);
                float a0 = 0.f, a1 = 0.f, a2 = 0.f, a3 = 0.f;
                #pragma unroll
                for (int j = 0; j < 16; ++j) {
                    float4 v = wr[j];
                    a0 += xs[4 * j]     * v.x;  a1 += xs[4 * j + 1] * v.y;
                    a2 += xs[4 * j + 2] * v.z;  a3 += xs[4 * j + 3] * v.w;
                }
                float s = wn[k] - ((a0 + a1) + (a2 + a3));
                if (s < bb) { bb = s; bi = k; }
            }
            #pragma unroll
            for (int off = 32; off > 0; off >>= 1) {   // lex (score,k) argmin
                float ob = __shfl_down(bb, off);
                int   oi = __shfl_down(bi, off);
                if (ob < bb || (ob == bb && oi < bi)) { bb = ob; bi = oi; }
            }
            if (lane == 0) bfin[lat] = bi;
        }
    }
    __syncthreads();

    // ---- Gather: out[n][:] = w[bfin][:]  (coalesced float4) ----
    float* outp = out + (size_t)blk * (LPB * DIM);
    #pragma unroll
    for (int r = 0; r < 8; ++r) {
        int idx = r * 256 + tid;
        int row = idx >> 4, seg = idx & 15;
        int code = bfin[row];
        *(float4*)&outp[idx * 4] = *(const float4*)&w[(size_t)code * DIM + seg * 4];
    }
}

extern "C" void kernel_launch(void* const* d_in, const int* in_sizes, int n_in,
                              void* d_out, int out_size, void* d_ws, size_t ws_size,
                              hipStream_t stream) {
    const float* x = (const float*)d_in[0];
    const float* w = (const float*)d_in[1];
    float* out = (float*)d_out;
    unsigned short* WEg = (unsigned short*)d_ws;                  // 262144 B (swizzled)
    float* wn = (float*)((char*)d_ws + 262144);                   // 4096 B

    vq_prep<<<4, 256, 0, stream>>>(w, WEg, wn);
    vq_main<<<NLAT / LPB, 256, 0, stream>>>(x, w, WEg, wn, out);
}